// Round 5
// baseline (30143.170 us; speedup 1.0000x reference)
//
#include <hip/hip_runtime.h>
#include <hip/hip_bf16.h>

// Problem constants
#define HH 1024
#define BB 128
#define TT 512
#define NWG 128      // persistent workgroups: (MP=4) x (NP=32)
#define NTH 512      // 8 waves: 4 output tiles (2M x 2N) x 2 K-halves
#define NP 32

typedef float        f32x4 __attribute__((ext_vector_type(4)));
typedef short        s16x8 __attribute__((ext_vector_type(8)));
typedef unsigned int u32x2 __attribute__((ext_vector_type(2)));

__device__ __forceinline__ unsigned short bf16b(float f) {
    union { __hip_bfloat16 h; unsigned short u; } cv;
    cv.h = __float2bfloat16(f);
    return cv.u;
}

__device__ __forceinline__ float gelu_exact(float x) {
    return 0.5f * x * (1.0f + erff(x * 0.70710678118654752440f));
}

// --- device-coherent (L1+L2-bypass) accesses: producer/consumer data across
// WGs within one kernel. Keeps L2 clean for weights.
__device__ __forceinline__ void sc_load_b16x8(s16x8& v, const unsigned short* p) {
    asm volatile("global_load_dwordx4 %0, %1, off sc0 sc1" : "=v"(v) : "v"(p));
}
__device__ __forceinline__ void sc_load_u32x2(u32x2& v, const unsigned* p) {
    asm volatile("global_load_dwordx2 %0, %1, off sc0 sc1" : "=v"(v) : "v"(p));
}
__device__ __forceinline__ void sc_store_b16(unsigned short* p, unsigned int v) {
    asm volatile("global_store_short %0, %1, off sc0 sc1" :: "v"(p), "v"(v) : "memory");
}
__device__ __forceinline__ void sc_store_u32(unsigned* p, unsigned int v) {
    asm volatile("global_store_dword %0, %1, off sc0 sc1" :: "v"(p), "v"(v) : "memory");
}
// --- non-temporal (no L2 pollution) for streaming X reads / Out writes.
__device__ __forceinline__ void nt_load_f32x4(f32x4& v, const float* p) {
    asm volatile("global_load_dwordx4 %0, %1, off nt" : "=v"(v) : "v"(p));
}
__device__ __forceinline__ void nt_load_f32(float& v, const float* p) {
    asm volatile("global_load_dword %0, %1, off nt" : "=v"(v) : "v"(p));
}
__device__ __forceinline__ void nt_store_f32(float* p, float v) {
    asm volatile("global_store_dword %0, %1, off nt" :: "v"(p), "v"(v) : "memory");
}
__device__ __forceinline__ void vm_wait0() {
    asm volatile("s_waitcnt vmcnt(0)" ::: "memory");
    __builtin_amdgcn_sched_barrier(0);   // rule #18: block motion across the wait
}

// ---------------------------------------------------------------------------
// Pack fp32 weight W[K][N] (row-major) into MFMA B-fragment layout, bf16:
//   P[((ntile*KT + ktile)*64 + lane)*8 + j] =
//       bf16(W[ktile*32 + (lane>>4)*8 + j][ntile*16 + (lane&15)])
// ---------------------------------------------------------------------------
__global__ __launch_bounds__(256) void pack_w_kernel(const float* __restrict__ W,
                                                     unsigned short* __restrict__ P,
                                                     int K, int N) {
    int tid = blockIdx.x * 256 + threadIdx.x;
    int KT = K >> 5;
    int total = (N >> 4) * KT * 64;
    if (tid >= total) return;
    int lane  = tid & 63;
    int ktile = (tid >> 6) % KT;
    int ntile = (tid >> 6) / KT;
    int k0 = ktile * 32 + (lane >> 4) * 8;
    int n  = ntile * 16 + (lane & 15);
    unsigned short tmp[8];
#pragma unroll
    for (int j = 0; j < 8; ++j)
        tmp[j] = bf16b(W[(size_t)(k0 + j) * N + n]);
    *reinterpret_cast<s16x8*>(P + (size_t)tid * 8) = *reinterpret_cast<const s16x8*>(tmp);
}

// ---------------------------------------------------------------------------
// Flag-array device barrier, split into arrive / wait so callers can overlap
// work (e.g. next-step X prefetch) with the spin.
// ---------------------------------------------------------------------------
__device__ __forceinline__ void gbar_arrive(unsigned* slots, unsigned rnd) {
    asm volatile("s_waitcnt vmcnt(0)" ::: "memory");  // drain my sc-stores
    __syncthreads();                                   // all 8 waves drained
    if (threadIdx.x == 0)
        sc_store_u32(slots + blockIdx.x, rnd);
}
__device__ __forceinline__ void gbar_wait(unsigned* slots, unsigned rnd) {
    if (threadIdx.x < 64) {
        const unsigned* p = slots + (threadIdx.x << 1);
        bool done;
        do {
            u32x2 v;
            sc_load_u32x2(v, p);
            asm volatile("s_waitcnt vmcnt(0)" ::: "memory");
            done = __all(v.x >= rnd && v.y >= rnd);
        } while (!done);
    }
    __syncthreads();
}

// K-loop over a bf16 activation buffer read with device-coherent loads.
// Abase includes the wave's row offset (+ q*8); A k-offsets are blk-local.
// bp points at the FIRST B-fragment for this K-segment.
__device__ __forceinline__ f32x4 kloop_sc(const unsigned short* Abase,
                                          const unsigned short* bp,
                                          int nblk) {
    f32x4 acc = {};
    for (int blk = 0; blk < nblk; ++blk) {
        int kb = blk * 8;
        s16x8 a[8], b[8];
#pragma unroll
        for (int j = 0; j < 8; ++j)
            sc_load_b16x8(a[j], Abase + (size_t)(kb + j) * 32);
#pragma unroll
        for (int j = 0; j < 8; ++j)
            b[j] = *reinterpret_cast<const s16x8*>(bp + (size_t)(kb + j) * 512);
        vm_wait0();
#pragma unroll
        for (int j = 0; j < 8; ++j)
            acc = __builtin_amdgcn_mfma_f32_16x16x32_bf16(a[j], b[j], acc, 0, 0, 0);
    }
    return acc;
}

// K-loop with A-fragments from LDS (x_t staged once per step).
// xf = &xfrag[wm][0][lane], stride 64 fragments per kt. Weights cached (L2).
__device__ __forceinline__ f32x4 kloop_lds(const s16x8* xf, const unsigned short* bp) {
    f32x4 acc = {};
#pragma unroll 8
    for (int kt = 0; kt < 32; ++kt) {
        s16x8 a = xf[(size_t)kt * 64];
        s16x8 b = *reinterpret_cast<const s16x8*>(bp + (size_t)kt * 512);
        acc = __builtin_amdgcn_mfma_f32_16x16x32_bf16(a, b, acc, 0, 0, 0);
    }
    return acc;
}

// ---------------------------------------------------------------------------
// Persistent kernel. Partition per GEMM (M=128, N=1024):
//   ng = wg & 31 -> 32-col slice; mg = wg >> 5 -> 32-row slice.
//   (wg % 8 == ng % 8 keeps all M-copies of a weight slice on one XCD.)
// 8 waves: tile = w&3 (2M x 2N of 16x16), khalf = w>>2 splits K.
// khalf-1 partials reduced into khalf-0 via 4 KB LDS.
// Weights/biases: plain cached loads (L2-resident — nothing else allocates).
// X: nt loads, staged to LDS fragments once per step. Activations: sc0sc1.
// ---------------------------------------------------------------------------
__global__ __launch_bounds__(512, 1) void persist_kernel(
    const float* __restrict__ X,
    const unsigned short* __restrict__ p_a1, const float* __restrict__ ab1,
    const unsigned short* __restrict__ p_a2, const float* __restrict__ ab2,
    const unsigned short* __restrict__ p_g1, const float* __restrict__ gb1,
    const unsigned short* __restrict__ p_g2, const float* __restrict__ gb2,
    float* __restrict__ Out,
    unsigned short* state, unsigned short* h1, unsigned short* albf,
    unsigned short* h2,
    unsigned* slots)
{
    __shared__ s16x8 xfrag[2][32][64];   // 64 KB: x_t A-fragments, frag order
    __shared__ f32x4 red[4][64];         // 4 KB: split-K reduction

    const int wg    = blockIdx.x;
    const int ng    = wg & (NP - 1);
    const int mg    = wg >> 5;
    const int tid   = threadIdx.x;
    const int lane  = tid & 63;
    const int w     = tid >> 6;       // 0..7
    const int tile  = w & 3;          // 2M x 2N
    const int khalf = w >> 2;         // 0..1
    const int wm    = tile >> 1;
    const int wn    = tile & 1;
    const int r     = lane & 15;
    const int q     = lane >> 4;

    const int mrow  = mg * 32 + wm * 16;
    const int ncol  = ng * 32 + wn * 16;
    const int ntile = ncol >> 4;

    const size_t arow_off = (size_t)(mrow + r) * HH + q * 8;

    // X staging assignment: wave w covers m-tile (w&1), kt = (w>>1)*8 .. +7.
    const int smt  = w & 1;
    const int skt0 = (w >> 1) * 8;
    const float* xstage = X + (size_t)(mg * 32 + smt * 16 + r) * (TT * HH) + q * 8;

    const unsigned short* bpa1 = p_a1 + ((size_t)ntile * 64) * 512 + (size_t)lane * 8;
    const unsigned short* bpg1 = p_g1 + ((size_t)ntile * 64) * 512 + (size_t)lane * 8;
    const unsigned short* bpa2 = p_a2 + ((size_t)ntile * 32) * 512 + (size_t)lane * 8;
    const unsigned short* bpg2 = p_g2 + ((size_t)ntile * 32) * 512 + (size_t)lane * 8;

    const float biasA1 = ab1[ncol + r];
    const float biasA2 = ab2[ncol + r];
    const float biasG1 = gb1[ncol + r];
    const float biasG2 = gb2[ncol + r];

    const s16x8* xf = &xfrag[wm][0][lane];

    float al_reg[4] = {0.f, 0.f, 0.f, 0.f};   // fp32 'aligned' tile (khalf 0)
    f32x4 pf[8];                              // x prefetch registers
    unsigned rnd = 0;

    // ---- prologue: stage x_0 fragments into LDS ----
    {
        const float* xs = xstage;             // t = 0
#pragma unroll
        for (int i = 0; i < 8; ++i) {
            nt_load_f32x4(pf[i], xs + (skt0 + i) * 32);
        }
        f32x4 ph[8];
#pragma unroll
        for (int i = 0; i < 8; ++i) {
            nt_load_f32x4(ph[i], xs + (skt0 + i) * 32 + 4);
        }
        vm_wait0();
#pragma unroll
        for (int i = 0; i < 8; ++i) {
            s16x8 a;
#pragma unroll
            for (int j = 0; j < 4; ++j) {
                a[j]     = (short)bf16b(pf[i][j]);
                a[j + 4] = (short)bf16b(ph[i][j]);
            }
            xfrag[smt][skt0 + i][lane] = a;
        }
    }
    __syncthreads();

    for (int t = 0; t < TT; ++t) {
        // ------- G1: h1 = gelu(concat(x_t, state) @ aw1 + ab1), K=2048 -----
        {
            f32x4 acc;
            if (khalf == 0) acc = kloop_lds(xf, bpa1);            // K 0..1023 (x)
            else            acc = kloop_sc(state + arow_off,      // K 1024..2047
                                           bpa1 + (size_t)32 * 512, 4);
            if (khalf == 1) red[tile][lane] = acc;
            __syncthreads();
            if (khalf == 0) {
                acc += red[tile][lane];
#pragma unroll
                for (int j = 0; j < 4; ++j) {
                    float v = acc[j] + biasA1;
                    sc_store_b16(h1 + (size_t)(mrow + q * 4 + j) * HH + ncol + r,
                                 bf16b(gelu_exact(v)));
                }
            }
        }
        ++rnd; gbar_arrive(slots, rnd); gbar_wait(slots, rnd);

        // ------- G2: aligned = h1 @ aw2 + ab2, K=1024 ----------------------
        {
            f32x4 acc = kloop_sc(h1 + arow_off + (size_t)khalf * 512,
                                 bpa2 + (size_t)khalf * 16 * 512, 2);
            if (khalf == 1) red[tile][lane] = acc;
            __syncthreads();
            if (khalf == 0) {
                acc += red[tile][lane];
#pragma unroll
                for (int j = 0; j < 4; ++j) {
                    float v = acc[j] + biasA2;
                    al_reg[j] = v;
                    sc_store_b16(albf + (size_t)(mrow + q * 4 + j) * HH + ncol + r,
                                 bf16b(v));
                }
            }
        }
        ++rnd; gbar_arrive(slots, rnd); gbar_wait(slots, rnd);

        // ------- G3: h2 = gelu(concat(x_t, aligned) @ gw1 + gb1), K=2048 ---
        {
            f32x4 acc;
            if (khalf == 0) acc = kloop_lds(xf, bpg1);
            else            acc = kloop_sc(albf + arow_off,
                                           bpg1 + (size_t)32 * 512, 4);
            if (khalf == 1) red[tile][lane] = acc;
            __syncthreads();
            if (khalf == 0) {
                acc += red[tile][lane];
#pragma unroll
                for (int j = 0; j < 4; ++j) {
                    float v = acc[j] + biasG1;
                    sc_store_b16(h2 + (size_t)(mrow + q * 4 + j) * HH + ncol + r,
                                 bf16b(gelu_exact(v)));
                }
            }
        }
        ++rnd; gbar_arrive(slots, rnd); gbar_wait(slots, rnd);

        // ------- G4: gate = sigmoid(h2 @ gw2 + gb2); blend; next state -----
        {
            f32x4 acc = kloop_sc(h2 + arow_off + (size_t)khalf * 512,
                                 bpg2 + (size_t)khalf * 16 * 512, 2);
            if (khalf == 1) red[tile][lane] = acc;
            __syncthreads();
            if (khalf == 0) {
                float xv[4];
#pragma unroll
                for (int j = 0; j < 4; ++j)
                    nt_load_f32(xv[j], X + (size_t)(mrow + q * 4 + j) * (TT * HH)
                                         + (size_t)t * HH + ncol + r);
                acc += red[tile][lane];
                vm_wait0();
#pragma unroll
                for (int j = 0; j < 4; ++j) {
                    int row = mrow + q * 4 + j;
                    int col = ncol + r;
                    float gl = acc[j] + biasG2;
                    float g  = 1.0f / (1.0f + expf(-gl));
                    float o  = g * al_reg[j] + (1.0f - g) * xv[j];
                    nt_store_f32(Out + (size_t)row * (TT * HH) + (size_t)t * HH + col, o);
                    sc_store_b16(state + (size_t)row * HH + col, bf16b(o));
                }
            }
        }
        ++rnd;
        gbar_arrive(slots, rnd);
        // Prefetch x_{t+1} while the barrier spins (loads are untracked asm;
        // completion enforced by vm_wait0 after the wait).
        f32x4 ph[8];
        if (t + 1 < TT) {
            const float* xs = xstage + (size_t)(t + 1) * HH;
#pragma unroll
            for (int i = 0; i < 8; ++i)
                nt_load_f32x4(pf[i], xs + (skt0 + i) * 32);
#pragma unroll
            for (int i = 0; i < 8; ++i)
                nt_load_f32x4(ph[i], xs + (skt0 + i) * 32 + 4);
        }
        gbar_wait(slots, rnd);
        if (t + 1 < TT) {
            vm_wait0();
#pragma unroll
            for (int i = 0; i < 8; ++i) {
                s16x8 a;
#pragma unroll
                for (int j = 0; j < 4; ++j) {
                    a[j]     = (short)bf16b(pf[i][j]);
                    a[j + 4] = (short)bf16b(ph[i][j]);
                }
                xfrag[smt][skt0 + i][lane] = a;
            }
            __syncthreads();   // xfrag ready for next G1
        }
    }
}

extern "C" void kernel_launch(void* const* d_in, const int* in_sizes, int n_in,
                              void* d_out, int out_size, void* d_ws, size_t ws_size,
                              hipStream_t stream) {
    (void)in_sizes; (void)n_in; (void)out_size; (void)ws_size;
    const float* X   = (const float*)d_in[0];
    const float* aw1 = (const float*)d_in[1];
    const float* ab1 = (const float*)d_in[2];
    const float* aw2 = (const float*)d_in[3];
    const float* ab2 = (const float*)d_in[4];
    const float* gw1 = (const float*)d_in[5];
    const float* gb1 = (const float*)d_in[6];
    const float* gw2 = (const float*)d_in[7];
    const float* gb2 = (const float*)d_in[8];
    float* Out = (float*)d_out;

    char* ws = (char*)d_ws;
    unsigned short* p_a1 = (unsigned short*)(ws);                 // 4 MB
    unsigned short* p_g1 = (unsigned short*)(ws + (4u  << 20));   // 4 MB
    unsigned short* p_a2 = (unsigned short*)(ws + (8u  << 20));   // 2 MB
    unsigned short* p_g2 = (unsigned short*)(ws + (10u << 20));   // 2 MB
    char* ctrl = ws + (12u << 20);
    unsigned* slots = (unsigned*)ctrl;                            // NWG u32
    unsigned short* state = (unsigned short*)(ctrl + 4096);       // 256 KB
    unsigned short* h1    = state + (size_t)BB * HH;              // 256 KB
    unsigned short* albf  = h1    + (size_t)BB * HH;              // 256 KB
    unsigned short* h2    = albf  + (size_t)BB * HH;              // 256 KB

    pack_w_kernel<<<(64 * 64 * 64 + 255) / 256, 256, 0, stream>>>(aw1, p_a1, 2048, 1024);
    pack_w_kernel<<<(64 * 64 * 64 + 255) / 256, 256, 0, stream>>>(gw1, p_g1, 2048, 1024);
    pack_w_kernel<<<(64 * 32 * 64 + 255) / 256, 256, 0, stream>>>(aw2, p_a2, 1024, 1024);
    pack_w_kernel<<<(64 * 32 * 64 + 255) / 256, 256, 0, stream>>>(gw2, p_g2, 1024, 1024);
    // Zero barrier slots + recurrent state every call (graph-replay safe).
    hipMemsetAsync(ctrl, 0, 4096 + (size_t)BB * HH * sizeof(unsigned short), stream);

    persist_kernel<<<NWG, NTH, 0, stream>>>(X, p_a1, ab1, p_a2, ab2,
                                            p_g1, gb1, p_g2, gb2,
                                            Out, state, h1, albf, h2,
                                            slots);
}